// Round 12
// baseline (335.634 us; speedup 1.0000x reference)
//
#include <hip/hip_runtime.h>
#include <hip/hip_bf16.h>
#include <math.h>

typedef __bf16 bf16_t;
typedef __bf16 bf16x8 __attribute__((ext_vector_type(8)));
typedef float f32x4 __attribute__((ext_vector_type(4)));

enum { EP_BF16 = 0, EP_SCORES = 1, EP_F32 = 2, EP_F32A = 3, EP_I32A = 4 };

#define MEMFENCE asm volatile("" ::: "memory")
#define BARRIER() do { MEMFENCE; __builtin_amdgcn_s_barrier(); MEMFENCE; } while (0)

__device__ __forceinline__ void gload_lds16(const void* g, void* l) {
  __builtin_amdgcn_global_load_lds(
      (const __attribute__((address_space(1))) void*)g,
      (__attribute__((address_space(3))) void*)l, 16, 0, 0);
}

template <int N>
__device__ __forceinline__ void wait_vmcnt() {
  if constexpr (N == 0)      asm volatile("s_waitcnt vmcnt(0)" ::: "memory");
  else if constexpr (N == 3) asm volatile("s_waitcnt vmcnt(3)" ::: "memory");
  else if constexpr (N == 8) asm volatile("s_waitcnt vmcnt(8)" ::: "memory");
  else static_assert(N == 0, "unsupported vmcnt");
}

// XCD-aware swizzle; requires nwg % 8 == 0
__device__ __forceinline__ int xcd_swz(int bid, int nwg) {
  const int q = nwg >> 3;
  return (bid & 7) * q + (bid >> 3);
}

// ---------------------------------------------------------------------------
// Deep-pipelined GEMM core.
// TM=8 (BM=256): 4 slots (128KB), two phases per K-tile, vmcnt(8).
// (TM=4 path retained but unused.)
// Per-K-tile cost is staging-bound (~2500 cyc @ 1 block/CU); TM=8 extracts
// 2x FLOP per staged K-tile vs TM=4 -> all GEMMs now use TM=8.
// ---------------------------------------------------------------------------

template <int TM, bool STG, int WAITN>
__device__ __forceinline__ void do_tile(char* smem, int slot, int sslot, size_t stoff,
                                        const char* const* gbase, const int* lbase,
                                        const int* aoff, const int* boff,
                                        f32x4 (&acc)[TM][4]) {
  bf16x8 bfr[4], af[4];
  if constexpr (TM == 8) {
    // ---- phase A: M-half 0 ----
#pragma unroll
    for (int n = 0; n < 4; ++n) bfr[n] = *(const bf16x8*)(smem + slot + boff[n]);
#pragma unroll
    for (int m = 0; m < 4; ++m) af[m] = *(const bf16x8*)(smem + slot + aoff[m]);
    if constexpr (STG) {
      gload_lds16(gbase[0] + stoff, smem + sslot + lbase[0]);
      gload_lds16(gbase[1] + stoff, smem + sslot + lbase[1]);
    }
    BARRIER();
    asm volatile("s_waitcnt lgkmcnt(0)" ::: "memory");
    __builtin_amdgcn_sched_barrier(0);
    __builtin_amdgcn_s_setprio(1);
#pragma unroll
    for (int m = 0; m < 4; ++m)
#pragma unroll
      for (int n = 0; n < 4; ++n)
        acc[m][n] = __builtin_amdgcn_mfma_f32_16x16x32_bf16(af[m], bfr[n], acc[m][n], 0, 0, 0);
    __builtin_amdgcn_s_setprio(0);
    BARRIER();
    // ---- phase B: M-half 1 ----
#pragma unroll
    for (int m = 0; m < 4; ++m) af[m] = *(const bf16x8*)(smem + slot + aoff[4 + m]);
    if constexpr (STG) {
      gload_lds16(gbase[2] + stoff, smem + sslot + lbase[2]);
      gload_lds16(gbase[3] + stoff, smem + sslot + lbase[3]);
      wait_vmcnt<WAITN>();  // retire oldest in-flight tile
    }
    BARRIER();
    asm volatile("s_waitcnt lgkmcnt(0)" ::: "memory");
    __builtin_amdgcn_sched_barrier(0);
    __builtin_amdgcn_s_setprio(1);
#pragma unroll
    for (int m = 0; m < 4; ++m)
#pragma unroll
      for (int n = 0; n < 4; ++n)
        acc[4 + m][n] = __builtin_amdgcn_mfma_f32_16x16x32_bf16(af[m], bfr[n], acc[4 + m][n], 0, 0, 0);
    __builtin_amdgcn_s_setprio(0);
    BARRIER();
  } else {
    // ---- single phase (TM=4, unused) ----
#pragma unroll
    for (int n = 0; n < 4; ++n) bfr[n] = *(const bf16x8*)(smem + slot + boff[n]);
#pragma unroll
    for (int m = 0; m < 4; ++m) af[m] = *(const bf16x8*)(smem + slot + aoff[m]);
    if constexpr (STG) {
      gload_lds16(gbase[0] + stoff, smem + sslot + lbase[0]);
      gload_lds16(gbase[1] + stoff, smem + sslot + lbase[1]);
      gload_lds16(gbase[2] + stoff, smem + sslot + lbase[2]);
      wait_vmcnt<WAITN>();
    }
    BARRIER();
    asm volatile("s_waitcnt lgkmcnt(0)" ::: "memory");
    __builtin_amdgcn_sched_barrier(0);
    __builtin_amdgcn_s_setprio(1);
#pragma unroll
    for (int m = 0; m < 4; ++m)
#pragma unroll
      for (int n = 0; n < 4; ++n)
        acc[m][n] = __builtin_amdgcn_mfma_f32_16x16x32_bf16(af[m], bfr[n], acc[m][n], 0, 0, 0);
    __builtin_amdgcn_s_setprio(0);
    BARRIER();
  }
}

template <int TM, int EPI>
__device__ __forceinline__ void gemm_core(
    const bf16_t* __restrict__ A, const bf16_t* __restrict__ B,
    void* __restrict__ Cout, int Nout, int kstride, int klen,
    int row0, int col0, bool causal, float scale, char* smem)
{
  constexpr int BM = TM * 32;
  constexpr int LPT_A = BM / 128;
  constexpr int LPT = LPT_A + 2;
  constexpr int ABYTES = BM * 64;
  constexpr int SLOT = (BM + 256) * 64;
  constexpr int NSLOT = (TM == 8) ? 4 : 3;
  constexpr int DEPTH = NSLOT - 1;
  constexpr int WAITN = (DEPTH - 1) * LPT;   // TM8: 8, TM4: 3

  const int tid = threadIdx.x;
  const int w = tid >> 6, lane = tid & 63;
  const int wr = w >> 2, wc = w & 3;

  const int nt = klen >> 5;

  const char* gbase[LPT];
  int lbase[LPT];
  {
    const int sd = (tid & 3) ^ ((tid >> 3) & 3);
    const int rrow = tid >> 2;
#pragma unroll
    for (int r = 0; r < LPT; ++r) {
      const bool isA = (r < LPT_A);
      const int rr = isA ? r : (r - LPT_A);
      const int grow = (isA ? row0 : col0) + rr * 128 + rrow;
      const bf16_t* op = isA ? A : B;
      gbase[r] = (const char*)(op + (size_t)grow * kstride) + sd * 16;
      lbase[r] = (isA ? 0 : ABYTES) + rr * 8192 + w * 1024;
    }
  }

  const int fl = lane & 15;
  const int arow_off = fl * 64 + (((lane >> 4) ^ ((fl >> 1) & 3)) * 16);
  int aoff[TM], boff[4];
#pragma unroll
  for (int m = 0; m < TM; ++m) aoff[m] = (wr * (TM * 16) + m * 16) * 64 + arow_off;
#pragma unroll
  for (int n = 0; n < 4; ++n) boff[n] = ABYTES + (wc * 64 + n * 16) * 64 + arow_off;

  f32x4 acc[TM][4] = {};

  const int npro = nt < DEPTH ? nt : DEPTH;
  for (int t = 0; t < npro; ++t)
#pragma unroll
    for (int r = 0; r < LPT; ++r)
      gload_lds16(gbase[r] + (size_t)t * 64, smem + (t % NSLOT) * SLOT + lbase[r]);

  const int nmain = nt - DEPTH;
  if (nmain > 0) {
    wait_vmcnt<WAITN>();
    BARRIER();
    for (int t = 0; t < nmain; ++t)
      do_tile<TM, true, WAITN>(smem, (t % NSLOT) * SLOT, ((t + DEPTH) % NSLOT) * SLOT,
                               (size_t)(t + DEPTH) * 64, gbase, lbase, aoff, boff, acc);
  }

  wait_vmcnt<0>();
  BARRIER();
  for (int t = nmain > 0 ? nmain : 0; t < nt; ++t)
    do_tile<TM, false, 0>(smem, (t % NSLOT) * SLOT, 0, 0, gbase, lbase, aoff, boff, acc);

  const int cr = (lane >> 4) * 4;
  const int cc = lane & 15;
#pragma unroll
  for (int m = 0; m < TM; ++m) {
#pragma unroll
    for (int n = 0; n < 4; ++n) {
#pragma unroll
      for (int i = 0; i < 4; ++i) {
        const int r = row0 + wr * (TM * 16) + m * 16 + cr + i;
        const int c = col0 + wc * 64 + n * 16 + cc;
        float v = acc[m][n][i];
        if (EPI == EP_BF16) {
          ((bf16_t*)Cout)[(size_t)r * Nout + c] = (bf16_t)v;
        } else if (EPI == EP_SCORES) {
          v *= scale;
          if (causal && c > r) v = -INFINITY;
          ((float*)Cout)[(size_t)r * Nout + c] = v;
        } else if (EPI == EP_F32) {
          ((float*)Cout)[(size_t)r * Nout + c] = v;
        } else if (EPI == EP_F32A) {
          atomicAdd((float*)Cout + (size_t)r * Nout + c, v);
        } else {
          // int32 fixed-point (2^-24): wrap-add is associative+commutative
          // => bit-deterministic for any piece count / arrival order.
          atomicAdd((int*)Cout + (size_t)r * Nout + c,
                    __float2int_rn(v * 16777216.0f));
        }
      }
    }
  }
}

// Launch A: q and k projections, exactly 256 blocks (128 q + 128 k)
__launch_bounds__(512, 2)
__global__ void qk_k(const bf16_t* __restrict__ qe16, const bf16_t* __restrict__ ie16,
                     const bf16_t* __restrict__ WqT, const bf16_t* __restrict__ WkT,
                     bf16_t* __restrict__ q16, bf16_t* __restrict__ k16) {
  extern __shared__ __align__(16) char smem[];
  int wg = xcd_swz(blockIdx.x, gridDim.x);
  const bf16_t *A, *B; bf16_t* C;
  if (wg < 128) { A = qe16; B = WqT; C = q16; }
  else          { A = ie16; B = WkT; C = k16; wg -= 128; }
  const int row0 = (wg >> 3) * 256, col0 = (wg & 7) * 256;  // M=4096, N=2048
  gemm_core<8, EP_BF16>(A, B, C, 2048, 2048, 2048, row0, col0, false, 1.f, smem);
}

// Launch B: causal grid 264 = 136 score tiles (TM=8, ~60us) + 128 v-jobs
// (TM=8, 64 tiles ~64us, fully hidden). non-causal grid 384 = 256 scores + 128 v.
__launch_bounds__(512, 2)
__global__ void vs_k(const bf16_t* __restrict__ WvT, const bf16_t* __restrict__ ie16,
                     const bf16_t* __restrict__ q16, const bf16_t* __restrict__ k16,
                     bf16_t* __restrict__ vT16, float* __restrict__ scores,
                     const int* __restrict__ maskflag) {
  extern __shared__ __align__(16) char smem[];
  const bool causal = maskflag[0] == 0;
  const int nsc = causal ? 136 : 256;
  const int bid = blockIdx.x;
  if (bid < nsc) {
    const int sid = xcd_swz(bid, nsc);  // 136 = 8*17, 256: both % 8 == 0
    int r, c;
    if (causal) {
      r = (int)((sqrtf(8.f * (float)sid + 1.f) - 1.f) * 0.5f);
      while ((r + 1) * (r + 2) / 2 <= sid) ++r;
      while (r * (r + 1) / 2 > sid) --r;
      c = sid - r * (r + 1) / 2;
    } else {
      r = sid >> 4; c = sid & 15;
    }
    gemm_core<8, EP_SCORES>(q16, k16, scores, 4096, 2048, 2048,
                            r * 256, c * 256, causal, 0.1f, smem);
  } else {
    const int j = bid - nsc;  // 0..127
    if (j >= 128) return;
    // vT16 [2048][4096] = WvT [2048][2048] x ie16^T; 8 row-bands x 16 cols
    gemm_core<8, EP_BF16>(WvT, ie16, vT16, 4096, 2048, 2048,
                          (j >> 4) * 256, (j & 15) * 256, false, 1.f, smem);
  }
}

// Launch C: pure softmax, 2 rows per 512-thread block, 2048 blocks.
__launch_bounds__(512, 4)
__global__ void sm_k(const float* __restrict__ scores, bf16_t* __restrict__ probs,
                     const int* __restrict__ maskflag) {
  const bool causal = maskflag[0] == 0;
  const int p = blockIdx.x;
  const int tid = threadIdx.x;
  const int h = tid >> 8;
  const int t = tid & 255;
  const int row = 2 * p + h;
  const int L = causal ? (row + 1) : 4096;
  const float* srow = scores + (size_t)row * 4096;
  float v[16];
  float m = -INFINITY;
#pragma unroll
  for (int j = 0; j < 16; ++j) {
    const int idx = t + j * 256;
    v[j] = (idx < L) ? srow[idx] : -INFINITY;
    m = fmaxf(m, v[j]);
  }
#pragma unroll
  for (int off = 32; off >= 1; off >>= 1) m = fmaxf(m, __shfl_xor(m, off));
  __shared__ float redm[8];
  __shared__ float reds[8];
  if ((tid & 63) == 0) redm[tid >> 6] = m;
  __syncthreads();
  m = fmaxf(fmaxf(redm[4 * h + 0], redm[4 * h + 1]),
            fmaxf(redm[4 * h + 2], redm[4 * h + 3]));
  float s = 0.f;
#pragma unroll
  for (int j = 0; j < 16; ++j) {
    v[j] = __expf(v[j] - m);   // exp(-inf - m) = 0 for masked entries
    s += v[j];
  }
#pragma unroll
  for (int off = 32; off >= 1; off >>= 1) s += __shfl_xor(s, off);
  if ((tid & 63) == 0) reds[tid >> 6] = s;
  __syncthreads();
  s = reds[4 * h + 0] + reds[4 * h + 1] + reds[4 * h + 2] + reds[4 * h + 3];
  const float inv = 1.f / s;
  bf16_t* prow = probs + (size_t)row * 4096;
#pragma unroll
  for (int j = 0; j < 16; ++j) prow[t + j * 256] = (bf16_t)(v[j] * inv);
}

// Launch D: out = probs @ v, TM=8 (BM=256, BN=256), int32 fixed-point atomics.
// Causal: 256 jobs = 8 cols x 32 pieces of exactly 34 K-tiles. Bands: 16 x
//   256 rows, band b has Keff=256(b+1) -> 8(b+1) tiles; tiles before band b:
//   cb = 4b(b+1); total 1088/col. Piece p covers band-major tile range
//   [34p, 34p+34) -> 1-4 gemm_core segments (one per overlapped band).
// Non-causal: 512 jobs = 8 cols x (16 bands x 4 pieces of 32 tiles).
__launch_bounds__(512, 2)
__global__ void pv_k(const bf16_t* __restrict__ probs, const bf16_t* __restrict__ vT16,
                     int* __restrict__ iout, const int* __restrict__ maskflag) {
  extern __shared__ __align__(16) char smem[];
  const bool causal = maskflag[0] == 0;
  const int bid = blockIdx.x;
  const int col = bid & 7;
  const int p = bid >> 3;
  if (causal) {
    if (p >= 32) return;
    const int t0g = p * 34, t1g = t0g + 34;
    for (int b = 0; b < 16; ++b) {
      const int cb = 4 * b * (b + 1);     // tiles before band b
      const int nb = 8 * (b + 1);         // tiles in band b
      const int s0 = max(t0g, cb), s1 = min(t1g, cb + nb);
      if (s0 < s1) {
        const int k0 = (s0 - cb) * 32;
        const int klen = (s1 - s0) * 32;
        gemm_core<8, EP_I32A>(probs + k0, vT16 + k0, iout, 2048, 4096, klen,
                              b * 256, col * 256, false, 1.f, smem);
        __syncthreads();
      }
      if (cb + nb >= t1g) break;
    }
  } else {
    if (p >= 64) return;
    const int band = p >> 2;
    const int k0 = (p & 3) * 1024;        // 32 tiles x 32 K
    gemm_core<8, EP_I32A>(probs + k0, vT16 + k0, iout, 2048, 4096, 1024,
                          band * 256, col * 256, false, 1.f, smem);
  }
}

// Launch E: in-place int32 -> fp32 on d_out (exactly S*D elements).
__global__ void cvtout_k(float* __restrict__ out, long n) {
  long i = ((long)blockIdx.x * blockDim.x + threadIdx.x) * 4;
  const long stride = (long)gridDim.x * blockDim.x * 4;
  for (; i < n; i += stride) {
    int4 v = *(const int4*)((const int*)out + i);
    float4 f;
    f.x = (float)v.x * (1.0f / 16777216.0f);
    f.y = (float)v.y * (1.0f / 16777216.0f);
    f.z = (float)v.z * (1.0f / 16777216.0f);
    f.w = (float)v.w * (1.0f / 16777216.0f);
    *(float4*)(out + i) = f;
  }
}

// ---------------------------------------------------------------------------

// y=0: qe->qe16 ; y=1: ie->ie16 ; y=2: zero d_out (int32 accumulator init)
__global__ void cvt_k(const float* __restrict__ qe, const float* __restrict__ ie,
                      bf16_t* __restrict__ qe16, bf16_t* __restrict__ ie16,
                      float* __restrict__ zout, long n) {
  const int y = blockIdx.y;
  long i = ((long)blockIdx.x * blockDim.x + threadIdx.x) * 8;
  const long stride = (long)gridDim.x * blockDim.x * 8;
  if (y == 2) {
    const float4 z = make_float4(0.f, 0.f, 0.f, 0.f);
    for (; i < n; i += stride) {
      *(float4*)(zout + i) = z;
      *(float4*)(zout + i + 4) = z;
    }
    return;
  }
  const float* x = y ? ie : qe;
  bf16_t* o = y ? ie16 : qe16;
  for (; i < n; i += stride) {
    const float4 a = *(const float4*)(x + i);
    const float4 b = *(const float4*)(x + i + 4);
    bf16x8 u;
    u[0] = (__bf16)a.x; u[1] = (__bf16)a.y; u[2] = (__bf16)a.z; u[3] = (__bf16)a.w;
    u[4] = (__bf16)b.x; u[5] = (__bf16)b.y; u[6] = (__bf16)b.z; u[7] = (__bf16)b.w;
    *(bf16x8*)(o + i) = u;
  }
}

// WT[n][k] = (bf16) W[k][n], z selects weight
__global__ void trans_k(const float* __restrict__ Wq, const float* __restrict__ Wk,
                        const float* __restrict__ Wv,
                        bf16_t* __restrict__ WqT, bf16_t* __restrict__ WkT,
                        bf16_t* __restrict__ WvT, int Dm) {
  const float* W = blockIdx.z == 0 ? Wq : (blockIdx.z == 1 ? Wk : Wv);
  bf16_t* WT = blockIdx.z == 0 ? WqT : (blockIdx.z == 1 ? WkT : WvT);
  __shared__ float tile[32][33];
  const int bx = blockIdx.x, by = blockIdx.y;
  const int tx = threadIdx.x & 31, ty = threadIdx.x >> 5;
#pragma unroll
  for (int r = ty; r < 32; r += 8)
    tile[r][tx] = W[(size_t)(by * 32 + r) * Dm + bx * 32 + tx];
  __syncthreads();
#pragma unroll
  for (int r = ty; r < 32; r += 8)
    WT[(size_t)(bx * 32 + r) * Dm + by * 32 + tx] = (bf16_t)tile[tx][r];
}

extern "C" void kernel_launch(void* const* d_in, const int* in_sizes, int n_in,
                              void* d_out, int out_size, void* d_ws, size_t ws_size,
                              hipStream_t stream) {
  const float* ie = (const float*)d_in[0];
  const float* qe = (const float*)d_in[1];
  const float* Wq = (const float*)d_in[2];
  const float* Wk = (const float*)d_in[3];
  const float* Wv = (const float*)d_in[4];
  const int* mask = (const int*)d_in[5];
  float* out = (float*)d_out;

  const int S = 4096, D = 2048;
  char* ws = (char*)d_ws;
  const size_t MB = 1u << 20;
  bf16_t* q16  = (bf16_t*)(ws + 0 * MB);
  bf16_t* k16  = (bf16_t*)(ws + 16 * MB);
  bf16_t* vT16 = (bf16_t*)(ws + 32 * MB);
  bf16_t* ie16 = (bf16_t*)(ws + 48 * MB);
  bf16_t* WvT  = (bf16_t*)(ws + 64 * MB);
  bf16_t* qe16 = (bf16_t*)(ws + 72 * MB);
  bf16_t* WqT  = (bf16_t*)(ws + 88 * MB);
  bf16_t* WkT  = (bf16_t*)(ws + 96 * MB);
  float*  scores = (float*)(ws + 72 * MB);   // overlays qe16/WqT/WkT after qk_k
  bf16_t* probs  = (bf16_t*)(ws + 0 * MB);   // overlays q16/k16 after scores

  hipFuncSetAttribute(reinterpret_cast<const void*>(&qk_k),
                      hipFuncAttributeMaxDynamicSharedMemorySize, 131072);
  hipFuncSetAttribute(reinterpret_cast<const void*>(&vs_k),
                      hipFuncAttributeMaxDynamicSharedMemorySize, 131072);
  hipFuncSetAttribute(reinterpret_cast<const void*>(&pv_k),
                      hipFuncAttributeMaxDynamicSharedMemorySize, 131072);

  // 1. casts + zero(d_out, as int32 accumulator) + weight transposes
  cvt_k<<<dim3(1024, 3), 256, 0, stream>>>(qe, ie, qe16, ie16, out, (long)S * D);
  trans_k<<<dim3(D / 32, D / 32, 3), 256, 0, stream>>>(Wq, Wk, Wv, WqT, WkT, WvT, D);

  // 2. q,k projections: exactly 256 blocks (~68us)
  qk_k<<<256, 512, 131072, stream>>>(qe16, ie16, WqT, WkT, q16, k16);

  // 3. scores (136 TM=8) + all 128 v-jobs (TM=8) hidden under them (~66us)
  vs_k<<<384, 512, 131072, stream>>>(WvT, ie16, q16, k16, vT16, scores, mask);

  // 4. pure softmax (~16us)
  sm_k<<<2048, 512, 0, stream>>>(scores, probs, mask);

  // 5. out = probs @ v, TM=8, 256 balanced jobs, int32 atomics (~45us)
  pv_k<<<512, 512, 131072, stream>>>(probs, vT16, (int*)out, mask);

  // 6. in-place int32 -> fp32 conversion of d_out
  cvtout_k<<<2048, 256, 0, stream>>>(out, (long)S * D);
}

// Round 13
// 304.579 us; speedup vs baseline: 1.1020x; 1.1020x over previous
//
#include <hip/hip_runtime.h>
#include <hip/hip_bf16.h>
#include <math.h>

typedef __bf16 bf16_t;
typedef __bf16 bf16x8 __attribute__((ext_vector_type(8)));
typedef float f32x4 __attribute__((ext_vector_type(4)));

enum { EP_BF16 = 0, EP_SCORES = 1, EP_F32 = 2, EP_F32A = 3, EP_I32A = 4 };

#define MEMFENCE asm volatile("" ::: "memory")
#define BARRIER() do { MEMFENCE; __builtin_amdgcn_s_barrier(); MEMFENCE; } while (0)

__device__ __forceinline__ void gload_lds16(const void* g, void* l) {
  __builtin_amdgcn_global_load_lds(
      (const __attribute__((address_space(1))) void*)g,
      (__attribute__((address_space(3))) void*)l, 16, 0, 0);
}

template <int N>
__device__ __forceinline__ void wait_vmcnt() {
  if constexpr (N == 0)       asm volatile("s_waitcnt vmcnt(0)" ::: "memory");
  else if constexpr (N == 6)  asm volatile("s_waitcnt vmcnt(6)" ::: "memory");
  else if constexpr (N == 8)  asm volatile("s_waitcnt vmcnt(8)" ::: "memory");
  else if constexpr (N == 12) asm volatile("s_waitcnt vmcnt(12)" ::: "memory");
  else if constexpr (N == 16) asm volatile("s_waitcnt vmcnt(16)" ::: "memory");
  else static_assert(N == 0, "unsupported vmcnt");
}

// XCD-aware swizzle; requires nwg % 8 == 0
__device__ __forceinline__ int xcd_swz(int bid, int nwg) {
  const int q = nwg >> 3;
  return (bid & 7) * q + (bid >> 3);
}

// ---------------------------------------------------------------------------
// Deep-pipelined GEMM core (round-7 proven).
// TM=8 (BM=256): NSLOT=4 (128KB), two phases per K-tile, vmcnt(8).
// TM=4 (BM=128): NSLOT=6 (144KB), depth-5, vmcnt(12).
// ---------------------------------------------------------------------------

template <int TM, bool STG, int WAITN>
__device__ __forceinline__ void do_tile(char* smem, int slot, int sslot, size_t stoff,
                                        const char* const* gbase, const int* lbase,
                                        const int* aoff, const int* boff,
                                        f32x4 (&acc)[TM][4]) {
  bf16x8 bfr[4], af[4];
  if constexpr (TM == 8) {
    // ---- phase A: M-half 0 ----
#pragma unroll
    for (int n = 0; n < 4; ++n) bfr[n] = *(const bf16x8*)(smem + slot + boff[n]);
#pragma unroll
    for (int m = 0; m < 4; ++m) af[m] = *(const bf16x8*)(smem + slot + aoff[m]);
    if constexpr (STG) {
      gload_lds16(gbase[0] + stoff, smem + sslot + lbase[0]);
      gload_lds16(gbase[1] + stoff, smem + sslot + lbase[1]);
    }
    BARRIER();
    asm volatile("s_waitcnt lgkmcnt(0)" ::: "memory");
    __builtin_amdgcn_sched_barrier(0);
    __builtin_amdgcn_s_setprio(1);
#pragma unroll
    for (int m = 0; m < 4; ++m)
#pragma unroll
      for (int n = 0; n < 4; ++n)
        acc[m][n] = __builtin_amdgcn_mfma_f32_16x16x32_bf16(af[m], bfr[n], acc[m][n], 0, 0, 0);
    __builtin_amdgcn_s_setprio(0);
    BARRIER();
    // ---- phase B: M-half 1 ----
#pragma unroll
    for (int m = 0; m < 4; ++m) af[m] = *(const bf16x8*)(smem + slot + aoff[4 + m]);
    if constexpr (STG) {
      gload_lds16(gbase[2] + stoff, smem + sslot + lbase[2]);
      gload_lds16(gbase[3] + stoff, smem + sslot + lbase[3]);
      wait_vmcnt<WAITN>();  // retire oldest in-flight tile
    }
    BARRIER();
    asm volatile("s_waitcnt lgkmcnt(0)" ::: "memory");
    __builtin_amdgcn_sched_barrier(0);
    __builtin_amdgcn_s_setprio(1);
#pragma unroll
    for (int m = 0; m < 4; ++m)
#pragma unroll
      for (int n = 0; n < 4; ++n)
        acc[4 + m][n] = __builtin_amdgcn_mfma_f32_16x16x32_bf16(af[m], bfr[n], acc[4 + m][n], 0, 0, 0);
    __builtin_amdgcn_s_setprio(0);
    BARRIER();
  } else {
    // ---- single phase ----
#pragma unroll
    for (int n = 0; n < 4; ++n) bfr[n] = *(const bf16x8*)(smem + slot + boff[n]);
#pragma unroll
    for (int m = 0; m < 4; ++m) af[m] = *(const bf16x8*)(smem + slot + aoff[m]);
    if constexpr (STG) {
      gload_lds16(gbase[0] + stoff, smem + sslot + lbase[0]);
      gload_lds16(gbase[1] + stoff, smem + sslot + lbase[1]);
      gload_lds16(gbase[2] + stoff, smem + sslot + lbase[2]);
      wait_vmcnt<WAITN>();
    }
    BARRIER();
    asm volatile("s_waitcnt lgkmcnt(0)" ::: "memory");
    __builtin_amdgcn_sched_barrier(0);
    __builtin_amdgcn_s_setprio(1);
#pragma unroll
    for (int m = 0; m < 4; ++m)
#pragma unroll
      for (int n = 0; n < 4; ++n)
        acc[m][n] = __builtin_amdgcn_mfma_f32_16x16x32_bf16(af[m], bfr[n], acc[m][n], 0, 0, 0);
    __builtin_amdgcn_s_setprio(0);
    BARRIER();
  }
}

template <int TM, int EPI, int NSLOT>
__device__ __forceinline__ void gemm_core(
    const bf16_t* __restrict__ A, const bf16_t* __restrict__ B,
    void* __restrict__ Cout, int Nout, int kstride, int klen,
    int row0, int col0, bool causal, float scale, char* smem)
{
  constexpr int BM = TM * 32;
  constexpr int LPT_A = BM / 128;        // staging rounds for A (8KB each)
  constexpr int LPT = LPT_A + 2;         // + 2 rounds for B (256 rows)
  constexpr int ABYTES = BM * 64;        // A bytes per slot
  constexpr int SLOT = (BM + 256) * 64;  // slot bytes
  constexpr int DEPTH = NSLOT - 1;       // stage-ahead distance (tiles)
  constexpr int WAITN = (DEPTH - 1) * LPT;

  const int tid = threadIdx.x;
  const int w = tid >> 6, lane = tid & 63;
  const int wr = w >> 2, wc = w & 3;

  const int nt = klen >> 5;

  // --- staging addresses (pre-swizzled global source, linear LDS dest) ---
  const char* gbase[LPT];
  int lbase[LPT];
  {
    const int sd = (tid & 3) ^ ((tid >> 3) & 3);  // swizzled k-slot (involution)
    const int rrow = tid >> 2;                    // 0..127
#pragma unroll
    for (int r = 0; r < LPT; ++r) {
      const bool isA = (r < LPT_A);
      const int rr = isA ? r : (r - LPT_A);
      const int grow = (isA ? row0 : col0) + rr * 128 + rrow;
      const bf16_t* op = isA ? A : B;
      gbase[r] = (const char*)(op + (size_t)grow * kstride) + sd * 16;
      lbase[r] = (isA ? 0 : ABYTES) + rr * 8192 + w * 1024;  // wave-uniform
    }
  }

  // --- fragment read offsets (swizzled, matches source pre-swizzle) ---
  const int fl = lane & 15;
  const int arow_off = fl * 64 + (((lane >> 4) ^ ((fl >> 1) & 3)) * 16);
  int aoff[TM], boff[4];
#pragma unroll
  for (int m = 0; m < TM; ++m) aoff[m] = (wr * (TM * 16) + m * 16) * 64 + arow_off;
#pragma unroll
  for (int n = 0; n < 4; ++n) boff[n] = ABYTES + (wc * 64 + n * 16) * 64 + arow_off;

  f32x4 acc[TM][4] = {};

  // --- prologue: stage tiles 0..DEPTH-1 ---
  const int npro = nt < DEPTH ? nt : DEPTH;
  for (int t = 0; t < npro; ++t)
#pragma unroll
    for (int r = 0; r < LPT; ++r)
      gload_lds16(gbase[r] + (size_t)t * 64, smem + (t % NSLOT) * SLOT + lbase[r]);

  // --- main loop: compute tile t, stage tile t+DEPTH ---
  const int nmain = nt - DEPTH;
  if (nmain > 0) {
    wait_vmcnt<WAITN>();
    BARRIER();
    for (int t = 0; t < nmain; ++t)
      do_tile<TM, true, WAITN>(smem, (t % NSLOT) * SLOT, ((t + DEPTH) % NSLOT) * SLOT,
                               (size_t)(t + DEPTH) * 64, gbase, lbase, aoff, boff, acc);
  }

  // --- drain: all staged; counted waits invalid here -> drain 0 ---
  wait_vmcnt<0>();
  BARRIER();
  for (int t = nmain > 0 ? nmain : 0; t < nt; ++t)
    do_tile<TM, false, 0>(smem, (t % NSLOT) * SLOT, 0, 0, gbase, lbase, aoff, boff, acc);

  // --- epilogue (C/D layout: col = lane&15, row = (lane>>4)*4 + i) ---
  const int cr = (lane >> 4) * 4;
  const int cc = lane & 15;
#pragma unroll
  for (int m = 0; m < TM; ++m) {
#pragma unroll
    for (int n = 0; n < 4; ++n) {
#pragma unroll
      for (int i = 0; i < 4; ++i) {
        const int r = row0 + wr * (TM * 16) + m * 16 + cr + i;
        const int c = col0 + wc * 64 + n * 16 + cc;
        float v = acc[m][n][i];
        if (EPI == EP_BF16) {
          ((bf16_t*)Cout)[(size_t)r * Nout + c] = (bf16_t)v;
        } else if (EPI == EP_SCORES) {
          v *= scale;
          if (causal && c > r) v = -INFINITY;
          ((float*)Cout)[(size_t)r * Nout + c] = v;
        } else if (EPI == EP_F32) {
          ((float*)Cout)[(size_t)r * Nout + c] = v;
        } else if (EPI == EP_F32A) {
          atomicAdd((float*)Cout + (size_t)r * Nout + c, v);
        } else {
          // int32 fixed-point (2^-24): wrap-add is associative+commutative
          // => bit-deterministic for any piece count / arrival order.
          atomicAdd((int*)Cout + (size_t)r * Nout + c,
                    __float2int_rn(v * 16777216.0f));
        }
      }
    }
  }
}

// Launch A: q and k projections, exactly 256 blocks (128 q + 128 k)
__launch_bounds__(512, 2)
__global__ void qk_k(const bf16_t* __restrict__ qe16, const bf16_t* __restrict__ ie16,
                     const bf16_t* __restrict__ WqT, const bf16_t* __restrict__ WkT,
                     bf16_t* __restrict__ q16, bf16_t* __restrict__ k16) {
  extern __shared__ __align__(16) char smem[];
  int wg = xcd_swz(blockIdx.x, gridDim.x);
  const bf16_t *A, *B; bf16_t* C;
  if (wg < 128) { A = qe16; B = WqT; C = q16; }
  else          { A = ie16; B = WkT; C = k16; wg -= 128; }
  const int row0 = (wg >> 3) * 256, col0 = (wg & 7) * 256;  // M=4096, N=2048
  gemm_core<8, EP_BF16, 4>(A, B, C, 2048, 2048, 2048, row0, col0, false, 1.f, smem);
}

// Launch B (grid 256): causal: 136 score tiles (TM=8) + 120 v-jobs (TM=4).
// non-causal: 256 score tiles.
__launch_bounds__(512, 2)
__global__ void vs_k(const bf16_t* __restrict__ WvT, const bf16_t* __restrict__ ie16,
                     const bf16_t* __restrict__ q16, const bf16_t* __restrict__ k16,
                     bf16_t* __restrict__ vT16, float* __restrict__ scores,
                     const int* __restrict__ maskflag) {
  extern __shared__ __align__(16) char smem[];
  const bool causal = maskflag[0] == 0;
  const int nsc = causal ? 136 : 256;
  const int bid = blockIdx.x;
  if (bid < nsc) {
    const int sid = xcd_swz(bid, nsc);  // 136 = 8*17, 256: both % 8 == 0
    int r, c;
    if (causal) {
      r = (int)((sqrtf(8.f * (float)sid + 1.f) - 1.f) * 0.5f);
      while ((r + 1) * (r + 2) / 2 <= sid) ++r;
      while (r * (r + 1) / 2 > sid) --r;
      c = sid - r * (r + 1) / 2;
    } else {
      r = sid >> 4; c = sid & 15;
    }
    gemm_core<8, EP_SCORES, 4>(q16, k16, scores, 4096, 2048, 2048,
                               r * 256, c * 256, causal, 0.1f, smem);
  } else {
    const int j = bid - nsc;  // 0..119 (causal only)
    // vT[d][s]: A = WvT [2048][2048], Bt = ie16 [4096][2048]
    gemm_core<4, EP_BF16, 6>(WvT, ie16, vT16, 4096, 2048, 2048,
                             (j >> 4) * 128, (j & 15) * 256, false, 1.f, smem);
  }
}

// Launch C (grid 2304): remaining v-jobs (causal: 136, non-causal: 256) +
// softmax (2 rows per 512-thread block, 2048 blocks). v dispatched first.
__launch_bounds__(512, 2)
__global__ void smv_k(const bf16_t* __restrict__ WvT, const bf16_t* __restrict__ ie16,
                      bf16_t* __restrict__ vT16,
                      const float* __restrict__ scores, bf16_t* __restrict__ probs,
                      const int* __restrict__ maskflag) {
  extern __shared__ __align__(16) char smem[];
  const bool causal = maskflag[0] == 0;
  const int nv = causal ? 136 : 256;
  const int vbase = causal ? 120 : 0;
  const int bid = blockIdx.x;
  if (bid < nv) {
    const int j = vbase + bid;
    gemm_core<4, EP_BF16, 6>(WvT, ie16, vT16, 4096, 2048, 2048,
                             (j >> 4) * 128, (j & 15) * 256, false, 1.f, smem);
    return;
  }
  const int p = bid - nv;
  if (p >= 2048) return;
  // --- softmax: rows 2p (threads 0-255) and 2p+1 (threads 256-511) ---
  const int tid = threadIdx.x;
  const int h = tid >> 8;          // half
  const int t = tid & 255;
  const int row = 2 * p + h;
  const int L = causal ? (row + 1) : 4096;
  const float* srow = scores + (size_t)row * 4096;
  float v[16];
  float m = -INFINITY;
#pragma unroll
  for (int j = 0; j < 16; ++j) {
    const int idx = t + j * 256;
    v[j] = (idx < L) ? srow[idx] : -INFINITY;
    m = fmaxf(m, v[j]);
  }
#pragma unroll
  for (int off = 32; off >= 1; off >>= 1) m = fmaxf(m, __shfl_xor(m, off));
  __shared__ float redm[8];
  __shared__ float reds[8];
  if ((tid & 63) == 0) redm[tid >> 6] = m;
  __syncthreads();
  m = fmaxf(fmaxf(redm[4 * h + 0], redm[4 * h + 1]),
            fmaxf(redm[4 * h + 2], redm[4 * h + 3]));
  float s = 0.f;
#pragma unroll
  for (int j = 0; j < 16; ++j) {
    v[j] = __expf(v[j] - m);   // exp(-inf - m) = 0 for masked entries
    s += v[j];
  }
#pragma unroll
  for (int off = 32; off >= 1; off >>= 1) s += __shfl_xor(s, off);
  if ((tid & 63) == 0) reds[tid >> 6] = s;
  __syncthreads();
  s = reds[4 * h + 0] + reds[4 * h + 1] + reds[4 * h + 2] + reds[4 * h + 3];
  const float inv = 1.f / s;
  bf16_t* prow = probs + (size_t)row * 4096;
#pragma unroll
  for (int j = 0; j < 16; ++j) prow[t + j * 256] = (bf16_t)(v[j] * inv);
}

// Launch D: out = probs @ v, TM=8, band-paired windows, int32 fixed-point.
// Causal: pair p in [0,8) = bands (p, 15-p): Klo=8(p+1) + Khi=128-8p = 136
//   K-tiles exactly -> 4 windows of exactly 34 tiles. Job = (pair,window,col):
//   window [34w,34w+34) crosses the lo/hi boundary at most once (Klo<=64<68)
//   -> at most 2 gemm_core segments. 8x4x8 = 256 jobs, all 34 tiles.
// Non-causal: 512 jobs = 8 cols x (16 bands x 4 pieces of 32 tiles).
__launch_bounds__(512, 2)
__global__ void pv_k(const bf16_t* __restrict__ probs, const bf16_t* __restrict__ vT16,
                     int* __restrict__ iout, const int* __restrict__ maskflag) {
  extern __shared__ __align__(16) char smem[];
  const bool causal = maskflag[0] == 0;
  const int bid = blockIdx.x;
  const int col = bid & 7;
  if (causal) {
    const int idx = bid >> 3;          // 0..31
    if (idx >= 32) return;
    const int p = idx >> 2;            // pair 0..7
    const int wnd = idx & 3;           // window 0..3
    const int blo = p, bhi = 15 - p;
    const int Klo = 8 * (p + 1);       // lo-band tiles
    const int Khi = 128 - 8 * p;       // hi-band tiles (sum = 136 = 4*34)
    const int w0 = 34 * wnd, w1 = w0 + 34;
    // lo segment
    const int l0 = w0, l1 = min(w1, Klo);
    if (l0 < l1) {
      gemm_core<8, EP_I32A, 4>(probs + l0 * 32, vT16 + l0 * 32, iout, 2048, 4096,
                               (l1 - l0) * 32, blo * 256, col * 256, false, 1.f, smem);
      __syncthreads();
    }
    // hi segment
    const int h0 = max(w0 - Klo, 0), h1 = min(w1 - Klo, Khi);
    if (h0 < h1) {
      gemm_core<8, EP_I32A, 4>(probs + h0 * 32, vT16 + h0 * 32, iout, 2048, 4096,
                               (h1 - h0) * 32, bhi * 256, col * 256, false, 1.f, smem);
    }
  } else {
    const int q = bid >> 3;
    if (q >= 64) return;
    const int band = q >> 2;
    const int k0 = (q & 3) * 1024;     // 32 tiles x 32 K
    gemm_core<8, EP_I32A, 4>(probs + k0, vT16 + k0, iout, 2048, 4096, 1024,
                             band * 256, col * 256, false, 1.f, smem);
  }
}

// Launch E: in-place int32 -> fp32 on d_out (exactly S*D elements).
__global__ void cvtout_k(float* __restrict__ out, long n) {
  long i = ((long)blockIdx.x * blockDim.x + threadIdx.x) * 4;
  const long stride = (long)gridDim.x * blockDim.x * 4;
  for (; i < n; i += stride) {
    int4 v = *(const int4*)((const int*)out + i);
    float4 f;
    f.x = (float)v.x * (1.0f / 16777216.0f);
    f.y = (float)v.y * (1.0f / 16777216.0f);
    f.z = (float)v.z * (1.0f / 16777216.0f);
    f.w = (float)v.w * (1.0f / 16777216.0f);
    *(float4*)(out + i) = f;
  }
}

// ---------------------------------------------------------------------------

// y=0: qe->qe16 ; y=1: ie->ie16 ; y=2: zero d_out (int32 accumulator init)
__global__ void cvt_k(const float* __restrict__ qe, const float* __restrict__ ie,
                      bf16_t* __restrict__ qe16, bf16_t* __restrict__ ie16,
                      float* __restrict__ zout, long n) {
  const int y = blockIdx.y;
  long i = ((long)blockIdx.x * blockDim.x + threadIdx.x) * 8;
  const long stride = (long)gridDim.x * blockDim.x * 8;
  if (y == 2) {
    const float4 z = make_float4(0.f, 0.f, 0.f, 0.f);
    for (; i < n; i += stride) {
      *(float4*)(zout + i) = z;
      *(float4*)(zout + i + 4) = z;
    }
    return;
  }
  const float* x = y ? ie : qe;
  bf16_t* o = y ? ie16 : qe16;
  for (; i < n; i += stride) {
    const float4 a = *(const float4*)(x + i);
    const float4 b = *(const float4*)(x + i + 4);
    bf16x8 u;
    u[0] = (__bf16)a.x; u[1] = (__bf16)a.y; u[2] = (__bf16)a.z; u[3] = (__bf16)a.w;
    u[4] = (__bf16)b.x; u[5] = (__bf16)b.y; u[6] = (__bf16)b.z; u[7] = (__bf16)b.w;
    *(bf16x8*)(o + i) = u;
  }
}

// WT[n][k] = (bf16) W[k][n], z selects weight
__global__ void trans_k(const float* __restrict__ Wq, const float* __restrict__ Wk,
                        const float* __restrict__ Wv,
                        bf16_t* __restrict__ WqT, bf16_t* __restrict__ WkT,
                        bf16_t* __restrict__ WvT, int Dm) {
  const float* W = blockIdx.z == 0 ? Wq : (blockIdx.z == 1 ? Wk : Wv);
  bf16_t* WT = blockIdx.z == 0 ? WqT : (blockIdx.z == 1 ? WkT : WvT);
  __shared__ float tile[32][33];
  const int bx = blockIdx.x, by = blockIdx.y;
  const int tx = threadIdx.x & 31, ty = threadIdx.x >> 5;
#pragma unroll
  for (int r = ty; r < 32; r += 8)
    tile[r][tx] = W[(size_t)(by * 32 + r) * Dm + bx * 32 + tx];
  __syncthreads();
#pragma unroll
  for (int r = ty; r < 32; r += 8)
    WT[(size_t)(bx * 32 + r) * Dm + by * 32 + tx] = (bf16_t)tile[tx][r];
}

extern "C" void kernel_launch(void* const* d_in, const int* in_sizes, int n_in,
                              void* d_out, int out_size, void* d_ws, size_t ws_size,
                              hipStream_t stream) {
  const float* ie = (const float*)d_in[0];
  const float* qe = (const float*)d_in[1];
  const float* Wq = (const float*)d_in[2];
  const float* Wk = (const float*)d_in[3];
  const float* Wv = (const float*)d_in[4];
  const int* mask = (const int*)d_in[5];
  float* out = (float*)d_out;

  const int S = 4096, D = 2048;
  char* ws = (char*)d_ws;
  const size_t MB = 1u << 20;
  bf16_t* q16  = (bf16_t*)(ws + 0 * MB);
  bf16_t* k16  = (bf16_t*)(ws + 16 * MB);
  bf16_t* vT16 = (bf16_t*)(ws + 32 * MB);
  bf16_t* ie16 = (bf16_t*)(ws + 48 * MB);
  bf16_t* WvT  = (bf16_t*)(ws + 64 * MB);
  bf16_t* qe16 = (bf16_t*)(ws + 72 * MB);
  bf16_t* WqT  = (bf16_t*)(ws + 88 * MB);
  bf16_t* WkT  = (bf16_t*)(ws + 96 * MB);
  float*  scores = (float*)(ws + 72 * MB);   // overlays qe16/WqT/WkT after qk_k
  bf16_t* probs  = (bf16_t*)(ws + 0 * MB);   // overlays q16/k16 after scores

  hipFuncSetAttribute(reinterpret_cast<const void*>(&qk_k),
                      hipFuncAttributeMaxDynamicSharedMemorySize, 131072);
  hipFuncSetAttribute(reinterpret_cast<const void*>(&vs_k),
                      hipFuncAttributeMaxDynamicSharedMemorySize, 147456);
  hipFuncSetAttribute(reinterpret_cast<const void*>(&smv_k),
                      hipFuncAttributeMaxDynamicSharedMemorySize, 147456);
  hipFuncSetAttribute(reinterpret_cast<const void*>(&pv_k),
                      hipFuncAttributeMaxDynamicSharedMemorySize, 131072);

  // 1. casts + zero(d_out, as int32 accumulator) + weight transposes
  cvt_k<<<dim3(1024, 3), 256, 0, stream>>>(qe, ie, qe16, ie16, out, (long)S * D);
  trans_k<<<dim3(D / 32, D / 32, 3), 256, 0, stream>>>(Wq, Wk, Wv, WqT, WkT, WvT, D);

  // 2. q,k projections: exactly 256 blocks (~68us)
  qk_k<<<256, 512, 131072, stream>>>(qe16, ie16, WqT, WkT, q16, k16);

  // 3. scores (136 long) + first 120 v-jobs hidden under them (~66us)
  vs_k<<<256, 512, 147456, stream>>>(WvT, ie16, q16, k16, vT16, scores, mask);

  // 4. remaining v-jobs + softmax merged (~40us)
  smv_k<<<2304, 512, 147456, stream>>>(WvT, ie16, vT16, scores, probs, mask);

  // 5. out = probs @ v, TM=8 band-paired 256x34-tile jobs, int32 atomics (~45us)
  pv_k<<<512, 512, 131072, stream>>>(probs, vT16, (int*)out, mask);

  // 6. in-place int32 -> fp32 conversion of d_out
  cvtout_k<<<2048, 256, 0, stream>>>(out, (long)S * D);
}

// Round 14
// 268.103 us; speedup vs baseline: 1.2519x; 1.1361x over previous
//
#include <hip/hip_runtime.h>
#include <hip/hip_bf16.h>
#include <math.h>

typedef __bf16 bf16_t;
typedef __bf16 bf16x8 __attribute__((ext_vector_type(8)));
typedef float f32x4 __attribute__((ext_vector_type(4)));

enum { EP_BF16 = 0, EP_SCORES = 1, EP_F32 = 2, EP_F32A = 3, EP_I32A = 4 };

#define MEMFENCE asm volatile("" ::: "memory")
#define BARRIER() do { MEMFENCE; __builtin_amdgcn_s_barrier(); MEMFENCE; } while (0)

__device__ __forceinline__ void gload_lds16(const void* g, void* l) {
  __builtin_amdgcn_global_load_lds(
      (const __attribute__((address_space(1))) void*)g,
      (__attribute__((address_space(3))) void*)l, 16, 0, 0);
}

template <int N>
__device__ __forceinline__ void wait_vmcnt() {
  if constexpr (N == 0)       asm volatile("s_waitcnt vmcnt(0)" ::: "memory");
  else if constexpr (N == 6)  asm volatile("s_waitcnt vmcnt(6)" ::: "memory");
  else if constexpr (N == 8)  asm volatile("s_waitcnt vmcnt(8)" ::: "memory");
  else if constexpr (N == 12) asm volatile("s_waitcnt vmcnt(12)" ::: "memory");
  else static_assert(N == 0, "unsupported vmcnt");
}

// XCD-aware swizzle; requires nwg % 8 == 0
__device__ __forceinline__ int xcd_swz(int bid, int nwg) {
  const int q = nwg >> 3;
  return (bid & 7) * q + (bid >> 3);
}

// ---------------------------------------------------------------------------
// Deep-pipelined GEMM core (round-7 proven).
// TM=8 (BM=256): NSLOT=4 (128KB), two phases per K-tile, vmcnt(8).
// TM=4 (BM=128): NSLOT=6 (144KB), depth-5, vmcnt(12).
// ---------------------------------------------------------------------------

template <int TM, bool STG, int WAITN>
__device__ __forceinline__ void do_tile(char* smem, int slot, int sslot, size_t stoff,
                                        const char* const* gbase, const int* lbase,
                                        const int* aoff, const int* boff,
                                        f32x4 (&acc)[TM][4]) {
  bf16x8 bfr[4], af[4];
  if constexpr (TM == 8) {
    // ---- phase A: M-half 0 ----
#pragma unroll
    for (int n = 0; n < 4; ++n) bfr[n] = *(const bf16x8*)(smem + slot + boff[n]);
#pragma unroll
    for (int m = 0; m < 4; ++m) af[m] = *(const bf16x8*)(smem + slot + aoff[m]);
    if constexpr (STG) {
      gload_lds16(gbase[0] + stoff, smem + sslot + lbase[0]);
      gload_lds16(gbase[1] + stoff, smem + sslot + lbase[1]);
    }
    BARRIER();
    asm volatile("s_waitcnt lgkmcnt(0)" ::: "memory");
    __builtin_amdgcn_sched_barrier(0);
    __builtin_amdgcn_s_setprio(1);
#pragma unroll
    for (int m = 0; m < 4; ++m)
#pragma unroll
      for (int n = 0; n < 4; ++n)
        acc[m][n] = __builtin_amdgcn_mfma_f32_16x16x32_bf16(af[m], bfr[n], acc[m][n], 0, 0, 0);
    __builtin_amdgcn_s_setprio(0);
    BARRIER();
    // ---- phase B: M-half 1 ----
#pragma unroll
    for (int m = 0; m < 4; ++m) af[m] = *(const bf16x8*)(smem + slot + aoff[4 + m]);
    if constexpr (STG) {
      gload_lds16(gbase[2] + stoff, smem + sslot + lbase[2]);
      gload_lds16(gbase[3] + stoff, smem + sslot + lbase[3]);
      wait_vmcnt<WAITN>();  // retire oldest in-flight tile
    }
    BARRIER();
    asm volatile("s_waitcnt lgkmcnt(0)" ::: "memory");
    __builtin_amdgcn_sched_barrier(0);
    __builtin_amdgcn_s_setprio(1);
#pragma unroll
    for (int m = 0; m < 4; ++m)
#pragma unroll
      for (int n = 0; n < 4; ++n)
        acc[4 + m][n] = __builtin_amdgcn_mfma_f32_16x16x32_bf16(af[m], bfr[n], acc[4 + m][n], 0, 0, 0);
    __builtin_amdgcn_s_setprio(0);
    BARRIER();
  } else {
    // ---- single phase ----
#pragma unroll
    for (int n = 0; n < 4; ++n) bfr[n] = *(const bf16x8*)(smem + slot + boff[n]);
#pragma unroll
    for (int m = 0; m < 4; ++m) af[m] = *(const bf16x8*)(smem + slot + aoff[m]);
    if constexpr (STG) {
      gload_lds16(gbase[0] + stoff, smem + sslot + lbase[0]);
      gload_lds16(gbase[1] + stoff, smem + sslot + lbase[1]);
      gload_lds16(gbase[2] + stoff, smem + sslot + lbase[2]);
      wait_vmcnt<WAITN>();
    }
    BARRIER();
    asm volatile("s_waitcnt lgkmcnt(0)" ::: "memory");
    __builtin_amdgcn_sched_barrier(0);
    __builtin_amdgcn_s_setprio(1);
#pragma unroll
    for (int m = 0; m < 4; ++m)
#pragma unroll
      for (int n = 0; n < 4; ++n)
        acc[m][n] = __builtin_amdgcn_mfma_f32_16x16x32_bf16(af[m], bfr[n], acc[m][n], 0, 0, 0);
    __builtin_amdgcn_s_setprio(0);
    BARRIER();
  }
}

template <int TM, int EPI, int NSLOT>
__device__ __forceinline__ void gemm_core(
    const bf16_t* __restrict__ A, const bf16_t* __restrict__ B,
    void* __restrict__ Cout, int Nout, int kstride, int klen,
    int row0, int col0, bool causal, float scale, char* smem)
{
  constexpr int BM = TM * 32;
  constexpr int LPT_A = BM / 128;        // staging rounds for A (8KB each)
  constexpr int LPT = LPT_A + 2;         // + 2 rounds for B (256 rows)
  constexpr int ABYTES = BM * 64;        // A bytes per slot
  constexpr int SLOT = (BM + 256) * 64;  // slot bytes
  constexpr int DEPTH = NSLOT - 1;       // stage-ahead distance (tiles)
  constexpr int WAITN = (DEPTH - 1) * LPT;

  const int tid = threadIdx.x;
  const int w = tid >> 6, lane = tid & 63;
  const int wr = w >> 2, wc = w & 3;

  const int nt = klen >> 5;

  // --- staging addresses (pre-swizzled global source, linear LDS dest) ---
  const char* gbase[LPT];
  int lbase[LPT];
  {
    const int sd = (tid & 3) ^ ((tid >> 3) & 3);  // swizzled k-slot (involution)
    const int rrow = tid >> 2;                    // 0..127
#pragma unroll
    for (int r = 0; r < LPT; ++r) {
      const bool isA = (r < LPT_A);
      const int rr = isA ? r : (r - LPT_A);
      const int grow = (isA ? row0 : col0) + rr * 128 + rrow;
      const bf16_t* op = isA ? A : B;
      gbase[r] = (const char*)(op + (size_t)grow * kstride) + sd * 16;
      lbase[r] = (isA ? 0 : ABYTES) + rr * 8192 + w * 1024;  // wave-uniform
    }
  }

  // --- fragment read offsets (swizzled, matches source pre-swizzle) ---
  const int fl = lane & 15;
  const int arow_off = fl * 64 + (((lane >> 4) ^ ((fl >> 1) & 3)) * 16);
  int aoff[TM], boff[4];
#pragma unroll
  for (int m = 0; m < TM; ++m) aoff[m] = (wr * (TM * 16) + m * 16) * 64 + arow_off;
#pragma unroll
  for (int n = 0; n < 4; ++n) boff[n] = ABYTES + (wc * 64 + n * 16) * 64 + arow_off;

  f32x4 acc[TM][4] = {};

  // --- prologue: stage tiles 0..DEPTH-1 ---
  const int npro = nt < DEPTH ? nt : DEPTH;
  for (int t = 0; t < npro; ++t)
#pragma unroll
    for (int r = 0; r < LPT; ++r)
      gload_lds16(gbase[r] + (size_t)t * 64, smem + (t % NSLOT) * SLOT + lbase[r]);

  // --- main loop: compute tile t, stage tile t+DEPTH ---
  const int nmain = nt - DEPTH;
  if (nmain > 0) {
    wait_vmcnt<WAITN>();
    BARRIER();
    for (int t = 0; t < nmain; ++t)
      do_tile<TM, true, WAITN>(smem, (t % NSLOT) * SLOT, ((t + DEPTH) % NSLOT) * SLOT,
                               (size_t)(t + DEPTH) * 64, gbase, lbase, aoff, boff, acc);
  }

  // --- drain: all staged; counted waits invalid here -> drain 0 ---
  wait_vmcnt<0>();
  BARRIER();
  for (int t = nmain > 0 ? nmain : 0; t < nt; ++t)
    do_tile<TM, false, 0>(smem, (t % NSLOT) * SLOT, 0, 0, gbase, lbase, aoff, boff, acc);

  // --- epilogue (C/D layout: col = lane&15, row = (lane>>4)*4 + i) ---
  const int cr = (lane >> 4) * 4;
  const int cc = lane & 15;
#pragma unroll
  for (int m = 0; m < TM; ++m) {
#pragma unroll
    for (int n = 0; n < 4; ++n) {
#pragma unroll
      for (int i = 0; i < 4; ++i) {
        const int r = row0 + wr * (TM * 16) + m * 16 + cr + i;
        const int c = col0 + wc * 64 + n * 16 + cc;
        float v = acc[m][n][i];
        if (EPI == EP_BF16) {
          ((bf16_t*)Cout)[(size_t)r * Nout + c] = (bf16_t)v;
        } else if (EPI == EP_SCORES) {
          v *= scale;
          if (causal && c > r) v = -INFINITY;
          ((float*)Cout)[(size_t)r * Nout + c] = v;
        } else if (EPI == EP_F32) {
          ((float*)Cout)[(size_t)r * Nout + c] = v;
        } else if (EPI == EP_F32A) {
          atomicAdd((float*)Cout + (size_t)r * Nout + c, v);
        } else {
          // int32 fixed-point (2^-24): wrap-add is associative+commutative
          atomicAdd((int*)Cout + (size_t)r * Nout + c,
                    __float2int_rn(v * 16777216.0f));
        }
      }
    }
  }
}

// Launch A: q and k projections, exactly 256 blocks (128 q + 128 k)
__launch_bounds__(512, 2)
__global__ void qk_k(const bf16_t* __restrict__ qe16, const bf16_t* __restrict__ ie16,
                     const bf16_t* __restrict__ WqT, const bf16_t* __restrict__ WkT,
                     bf16_t* __restrict__ q16, bf16_t* __restrict__ k16) {
  extern __shared__ __align__(16) char smem[];
  int wg = xcd_swz(blockIdx.x, gridDim.x);
  const bf16_t *A, *B; bf16_t* C;
  if (wg < 128) { A = qe16; B = WqT; C = q16; }
  else          { A = ie16; B = WkT; C = k16; wg -= 128; }
  const int row0 = (wg >> 3) * 256, col0 = (wg & 7) * 256;  // M=4096, N=2048
  gemm_core<8, EP_BF16, 4>(A, B, C, 2048, 2048, 2048, row0, col0, false, 1.f, smem);
}

// Launch B (grid 256): causal: 136 score tiles + 120 TM=8 v-jobs = exactly 256
// one-per-CU blocks, all 64 K-tiles. v covers bands 0-6 full + band 7 cols 0-7.
// non-causal: 256 score tiles only.
__launch_bounds__(512, 2)
__global__ void vs_k(const bf16_t* __restrict__ WvT, const bf16_t* __restrict__ ie16,
                     const bf16_t* __restrict__ q16, const bf16_t* __restrict__ k16,
                     bf16_t* __restrict__ vT16, float* __restrict__ scores,
                     const int* __restrict__ maskflag) {
  extern __shared__ __align__(16) char smem[];
  const bool causal = maskflag[0] == 0;
  const int nsc = causal ? 136 : 256;
  const int bid = blockIdx.x;
  if (bid < nsc) {
    const int sid = xcd_swz(bid, nsc);  // 136 = 8*17, 256: both % 8 == 0
    int r, c;
    if (causal) {
      r = (int)((sqrtf(8.f * (float)sid + 1.f) - 1.f) * 0.5f);
      while ((r + 1) * (r + 2) / 2 <= sid) ++r;
      while (r * (r + 1) / 2 > sid) --r;
      c = sid - r * (r + 1) / 2;
    } else {
      r = sid >> 4; c = sid & 15;
    }
    gemm_core<8, EP_SCORES, 4>(q16, k16, scores, 4096, 2048, 2048,
                               r * 256, c * 256, causal, 0.1f, smem);
  } else {
    const int j = bid - nsc;  // 0..119 (causal only; grid=256)
    if (j >= 120) return;
    // vT16[d][s] = sum_k WvT[d][k] ie16[s][k]; bands of 256 d-rows x 16 s-cols
    gemm_core<8, EP_BF16, 4>(WvT, ie16, vT16, 4096, 2048, 2048,
                             (j >> 4) * 256, (j & 15) * 256, false, 1.f, smem);
  }
}

// Launch C: softmax (2048 blocks) + causal overflow v-work.
// Causal: bids 0..31 = 8 overflow tiles (band 7, cols 8-15) x 4 K-pieces of
//   512 K each, int32 fixed-point atomics into vT32 staging (zeroed by cvt_k).
//   ~2.1M atomics, ~17us of GEMM — hides under softmax's ~15us.
// Non-causal: bids 0..127 = all 128 v-jobs full-K (perf irrelevant).
__launch_bounds__(512, 2)
__global__ void smv3_k(const bf16_t* __restrict__ WvT, const bf16_t* __restrict__ ie16,
                       bf16_t* __restrict__ vT16, int* __restrict__ vT32i,
                       const float* __restrict__ scores, bf16_t* __restrict__ probs,
                       const int* __restrict__ maskflag) {
  extern __shared__ __align__(16) char smem[];
  const bool causal = maskflag[0] == 0;
  const int nv = causal ? 32 : 128;
  const int bid = blockIdx.x;
  if (bid < nv) {
    if (causal) {
      const int ov = bid & 7;          // overflow tile: band 7, col 8+ov
      const int piece = bid >> 3;      // 0..3, 512 K each
      const bf16_t* A = WvT + (size_t)1792 * 2048 + piece * 512;
      const bf16_t* B = ie16 + (size_t)(2048 + ov * 256) * 2048 + piece * 512;
      gemm_core<8, EP_I32A, 4>(A, B, vT32i + ov * 65536, 256, 2048, 512,
                               0, 0, false, 1.f, smem);
    } else {
      const int j = bid;
      gemm_core<8, EP_BF16, 4>(WvT, ie16, vT16, 4096, 2048, 2048,
                               (j >> 4) * 256, (j & 15) * 256, false, 1.f, smem);
    }
    return;
  }
  const int p = bid - nv;
  if (p >= 2048) return;
  // --- softmax: rows 2p (threads 0-255) and 2p+1 (threads 256-511) ---
  const int tid = threadIdx.x;
  const int h = tid >> 8;
  const int t = tid & 255;
  const int row = 2 * p + h;
  const int L = causal ? (row + 1) : 4096;
  const float* srow = scores + (size_t)row * 4096;
  float v[16];
  float m = -INFINITY;
#pragma unroll
  for (int j = 0; j < 16; ++j) {
    const int idx = t + j * 256;
    v[j] = (idx < L) ? srow[idx] : -INFINITY;
    m = fmaxf(m, v[j]);
  }
#pragma unroll
  for (int off = 32; off >= 1; off >>= 1) m = fmaxf(m, __shfl_xor(m, off));
  __shared__ float redm[8];
  __shared__ float reds[8];
  if ((tid & 63) == 0) redm[tid >> 6] = m;
  __syncthreads();
  m = fmaxf(fmaxf(redm[4 * h + 0], redm[4 * h + 1]),
            fmaxf(redm[4 * h + 2], redm[4 * h + 3]));
  float s = 0.f;
#pragma unroll
  for (int j = 0; j < 16; ++j) {
    v[j] = __expf(v[j] - m);   // exp(-inf - m) = 0 for masked entries
    s += v[j];
  }
#pragma unroll
  for (int off = 32; off >= 1; off >>= 1) s += __shfl_xor(s, off);
  if ((tid & 63) == 0) reds[tid >> 6] = s;
  __syncthreads();
  s = reds[4 * h + 0] + reds[4 * h + 1] + reds[4 * h + 2] + reds[4 * h + 3];
  const float inv = 1.f / s;
  bf16_t* prow = probs + (size_t)row * 4096;
#pragma unroll
  for (int j = 0; j < 16; ++j) prow[t + j * 256] = (bf16_t)(v[j] * inv);
}

// Patch kernel: convert the 8 overflow tiles from int32 staging into vT16.
// 8 x 256 x 256 cells; thread handles 8 consecutive cells. Causal only.
__global__ void cvt8_k(const int* __restrict__ vT32i, bf16_t* __restrict__ vT16,
                       const int* __restrict__ maskflag) {
  if (maskflag[0] != 0) return;
  const long i = ((long)blockIdx.x * blockDim.x + threadIdx.x) * 8;
  if (i >= 8L * 65536) return;
  const int tile = (int)(i >> 16);
  const int within = (int)(i & 65535);
  const int r = within >> 8, c = within & 255;
  const int4 a = *(const int4*)(vT32i + i);
  const int4 b = *(const int4*)(vT32i + i + 4);
  bf16x8 o;
  o[0] = (__bf16)((float)a.x * (1.0f / 16777216.0f));
  o[1] = (__bf16)((float)a.y * (1.0f / 16777216.0f));
  o[2] = (__bf16)((float)a.z * (1.0f / 16777216.0f));
  o[3] = (__bf16)((float)a.w * (1.0f / 16777216.0f));
  o[4] = (__bf16)((float)b.x * (1.0f / 16777216.0f));
  o[5] = (__bf16)((float)b.y * (1.0f / 16777216.0f));
  o[6] = (__bf16)((float)b.z * (1.0f / 16777216.0f));
  o[7] = (__bf16)((float)b.w * (1.0f / 16777216.0f));
  *(bf16x8*)(vT16 + (size_t)(1792 + r) * 4096 + (8 + tile) * 256 + c) = o;
}

// Launch D: out = probs @ v (round-7 proven).
// Causal: band-pairing balanced split-K, EXACTLY 256 jobs of ~2112 K each.
//   2 commutative fp32 adds per atomic cell; d_out pre-zeroed by cvt_k.
// Non-causal: 512 jobs, all bands split 2x2048 (atomic).
__launch_bounds__(512, 2)
__global__ void pv_k(const bf16_t* __restrict__ probs, const bf16_t* __restrict__ vT16,
                     float* __restrict__ out, const int* __restrict__ maskflag) {
  extern __shared__ __align__(16) char smem[];
  const bool causal = maskflag[0] == 0;
  const int bid = blockIdx.x;
  if (causal) {
    if (bid >= 256) return;
    const int sid  = xcd_swz(bid, 256);
    const int half = sid & 1;
    const int pair = (sid >> 1) & 15;
    const int col  = sid >> 5;            // 0..7
    const int blo = pair, bhi = 31 - pair;
    const int Klo = 128 * (blo + 1);
    const int cut = 2112 - Klo;           // >=64, multiple of 32
    if (half == 0) {
      gemm_core<4, EP_F32, 6>(probs, vT16, out, 2048, 4096, Klo,
                              blo * 128, col * 256, false, 1.f, smem);
      __syncthreads();  // all LDS reads of call 1 retired before slot reuse
      gemm_core<4, EP_F32A, 6>(probs, vT16, out, 2048, 4096, cut,
                               bhi * 128, col * 256, false, 1.f, smem);
    } else {
      gemm_core<4, EP_F32A, 6>(probs + cut, vT16 + cut, out, 2048, 4096, 2112,
                               bhi * 128, col * 256, false, 1.f, smem);
    }
  } else {
    if (bid >= 512) return;
    const int sid = xcd_swz(bid, 512);
    const int t = sid >> 1;
    const int band = t & 31, col = t >> 5;
    const int k0 = (sid & 1) ? 2048 : 0;
    gemm_core<4, EP_F32A, 6>(probs + k0, vT16 + k0, out, 2048, 4096, 2048,
                             band * 128, col * 256, false, 1.f, smem);
  }
}

// ---------------------------------------------------------------------------

// y=0: qe->qe16 ; y=1: ie->ie16 ; y=2: zero d_out ; y=3: zero vT32 staging
__global__ void cvt_k(const float* __restrict__ qe, const float* __restrict__ ie,
                      bf16_t* __restrict__ qe16, bf16_t* __restrict__ ie16,
                      float* __restrict__ zout, float* __restrict__ zv, long n) {
  const int y = blockIdx.y;
  long i = ((long)blockIdx.x * blockDim.x + threadIdx.x) * 8;
  const long stride = (long)gridDim.x * blockDim.x * 8;
  if (y >= 2) {
    float* z = (y == 2) ? zout : zv;
    const long nz = (y == 2) ? n : 8L * 65536;
    const float4 zero4 = make_float4(0.f, 0.f, 0.f, 0.f);
    for (; i < nz; i += stride) {
      *(float4*)(z + i) = zero4;
      *(float4*)(z + i + 4) = zero4;
    }
    return;
  }
  const float* x = y ? ie : qe;
  bf16_t* o = y ? ie16 : qe16;
  for (; i < n; i += stride) {
    const float4 a = *(const float4*)(x + i);
    const float4 b = *(const float4*)(x + i + 4);
    bf16x8 u;
    u[0] = (__bf16)a.x; u[1] = (__bf16)a.y; u[2] = (__bf16)a.z; u[3] = (__bf16)a.w;
    u[4] = (__bf16)b.x; u[5] = (__bf16)b.y; u[6] = (__bf16)b.z; u[7] = (__bf16)b.w;
    *(bf16x8*)(o + i) = u;
  }
}

// WT[n][k] = (bf16) W[k][n], z selects weight
__global__ void trans_k(const float* __restrict__ Wq, const float* __restrict__ Wk,
                        const float* __restrict__ Wv,
                        bf16_t* __restrict__ WqT, bf16_t* __restrict__ WkT,
                        bf16_t* __restrict__ WvT, int Dm) {
  const float* W = blockIdx.z == 0 ? Wq : (blockIdx.z == 1 ? Wk : Wv);
  bf16_t* WT = blockIdx.z == 0 ? WqT : (blockIdx.z == 1 ? WkT : WvT);
  __shared__ float tile[32][33];
  const int bx = blockIdx.x, by = blockIdx.y;
  const int tx = threadIdx.x & 31, ty = threadIdx.x >> 5;
#pragma unroll
  for (int r = ty; r < 32; r += 8)
    tile[r][tx] = W[(size_t)(by * 32 + r) * Dm + bx * 32 + tx];
  __syncthreads();
#pragma unroll
  for (int r = ty; r < 32; r += 8)
    WT[(size_t)(bx * 32 + r) * Dm + by * 32 + tx] = (bf16_t)tile[tx][r];
}

extern "C" void kernel_launch(void* const* d_in, const int* in_sizes, int n_in,
                              void* d_out, int out_size, void* d_ws, size_t ws_size,
                              hipStream_t stream) {
  const float* ie = (const float*)d_in[0];
  const float* qe = (const float*)d_in[1];
  const float* Wq = (const float*)d_in[2];
  const float* Wk = (const float*)d_in[3];
  const float* Wv = (const float*)d_in[4];
  const int* mask = (const int*)d_in[5];
  float* out = (float*)d_out;

  const int S = 4096, D = 2048;
  char* ws = (char*)d_ws;
  const size_t MB = 1u << 20;
  bf16_t* q16  = (bf16_t*)(ws + 0 * MB);
  bf16_t* k16  = (bf16_t*)(ws + 16 * MB);
  bf16_t* vT16 = (bf16_t*)(ws + 32 * MB);
  bf16_t* ie16 = (bf16_t*)(ws + 48 * MB);
  bf16_t* WvT  = (bf16_t*)(ws + 64 * MB);
  bf16_t* qe16 = (bf16_t*)(ws + 72 * MB);
  bf16_t* WqT  = (bf16_t*)(ws + 88 * MB);
  bf16_t* WkT  = (bf16_t*)(ws + 96 * MB);
  float*  scores = (float*)(ws + 72 * MB);   // overlays qe16/WqT/WkT after qk_k
  bf16_t* probs  = (bf16_t*)(ws + 0 * MB);   // overlays q16/k16 after scores
  float*  vT32   = (float*)(ws + 136 * MB);  // 2 MB int32/fp32 staging (8 tiles)

  hipFuncSetAttribute(reinterpret_cast<const void*>(&qk_k),
                      hipFuncAttributeMaxDynamicSharedMemorySize, 131072);
  hipFuncSetAttribute(reinterpret_cast<const void*>(&vs_k),
                      hipFuncAttributeMaxDynamicSharedMemorySize, 131072);
  hipFuncSetAttribute(reinterpret_cast<const void*>(&smv3_k),
                      hipFuncAttributeMaxDynamicSharedMemorySize, 131072);
  hipFuncSetAttribute(reinterpret_cast<const void*>(&pv_k),
                      hipFuncAttributeMaxDynamicSharedMemorySize, 147456);

  // 1. casts + zero(d_out for pv atomics, vT32 for overflow) + transposes
  cvt_k<<<dim3(1024, 4), 256, 0, stream>>>(qe, ie, qe16, ie16, out, vT32, (long)S * D);
  trans_k<<<dim3(D / 32, D / 32, 3), 256, 0, stream>>>(Wq, Wk, Wv, WqT, WkT, WvT, D);

  // 2. q,k projections: exactly 256 blocks (~68us)
  qk_k<<<256, 512, 131072, stream>>>(qe16, ie16, WqT, WkT, q16, k16);

  // 3. scores (136) + 120 TM=8 v-jobs = exactly 256 one-per-CU blocks (~68us)
  vs_k<<<256, 512, 131072, stream>>>(WvT, ie16, q16, k16, vT16, scores, mask);

  // 4. softmax + 32 overflow-v pieces (int32 atomics into vT32) (~18us)
  smv3_k<<<2176, 512, 131072, stream>>>(WvT, ie16, vT16, (int*)vT32, scores, probs, mask);

  // 5. patch the 8 overflow tiles into vT16 (~2us)
  cvt8_k<<<256, 256, 0, stream>>>((const int*)vT32, vT16, mask);

  // 6. out = probs @ v, band-paired split-K, 256 jobs (~70us)
  pv_k<<<512, 512, 147456, stream>>>(probs, vT16, out, mask);
}